// Round 3
// baseline (1447.322 us; speedup 1.0000x reference)
//
#include <hip/hip_runtime.h>

#define N_NODES 50000
#define N_EDGES 800000
#define HDIM 128

typedef unsigned short u16;
typedef unsigned int u32;
typedef __attribute__((ext_vector_type(8))) short short8;
typedef __attribute__((ext_vector_type(4))) float f32x4;
typedef __attribute__((ext_vector_type(2))) float f32x2;

__device__ __forceinline__ u16 f2bf(float f) {
    union { float f; u32 u; } v; v.f = f;
    u32 r = v.u + 0x7FFFu + ((v.u >> 16) & 1u);
    return (u16)(r >> 16);
}

__device__ __forceinline__ float bf2f(u16 h) {
    union { u32 u; float f; } v; v.u = ((u32)h) << 16;
    return v.f;
}

// ---- pack [128x128] row-major f32 -> bf16 B-fragments (mfma_f32_16x16x32_bf16)
// tile t (16 cols), chunk c (32 k): lane holds B[k=c*32+(lane>>4)*8+j][n=t*16+(lane&15)]
__device__ __forceinline__ void pack_one(const float* src, u16* dst, int g, int tOff) {
    int t = g >> 8;
    int c = (g >> 6) & 3;
    int lane = g & 63;
    int q = lane >> 4, n = lane & 15;
    const float* s = src + (size_t)(c * 32 + q * 8) * 128 + t * 16 + n;
    u16* dp = dst + ((((size_t)(t + tOff) * 4 + c) * 64 + lane) * 8);
#pragma unroll
    for (int j = 0; j < 8; ++j) dp[j] = f2bf(s[(size_t)j * 128]);
}

// 24 blocks: We = [W1|W2|W3] -> PB1 (16 tiles), PB3 (8 tiles)
__global__ __launch_bounds__(256) void pack_we(const float* __restrict__ We,
                                               u16* __restrict__ PB1,
                                               u16* __restrict__ PB3) {
    int f = blockIdx.x * 256 + threadIdx.x;
    int m = f >> 11;        // 0,1,2
    int g = f & 2047;
    if (m == 0)      pack_one(We,               PB1, g, 0);
    else if (m == 1) pack_one(We + 16384,       PB1, g, 8);
    else             pack_one(We + 32768,       PB3, g, 0);
}

__global__ __launch_bounds__(256) void pack_b(const float* __restrict__ src,
                                              u16* __restrict__ dst) {
    int g = blockIdx.x * 256 + threadIdx.x;
    if (g < 2048) pack_one(src, dst, g, 0);
}

__global__ void build_bias256(const float* __restrict__ be, float* __restrict__ b256) {
    int i = threadIdx.x;
    b256[i] = (i < 128) ? be[i] : 0.f;
}

// Wgo = Wg @ Wo (f32), bgo = bg @ Wo   (64 blocks x 256)
__global__ __launch_bounds__(256) void compute_wgo(const float* __restrict__ Wg,
                                                   const float* __restrict__ Wo,
                                                   const float* __restrict__ bg,
                                                   float* __restrict__ Wgo,
                                                   float* __restrict__ bgo) {
    int id = blockIdx.x * 256 + threadIdx.x;
    if (id < 16384) {
        int i = id >> 7, j = id & 127;
        float s = 0.f;
#pragma unroll 8
        for (int k = 0; k < 128; ++k) s += Wg[i * 128 + k] * Wo[k * 128 + j];
        Wgo[id] = s;
    }
    if (id < 128) {
        float s = 0.f;
        for (int k = 0; k < 128; ++k) s += bg[k] * Wo[k * 128 + id];
        bgo[id] = s;
    }
}

// ---- counting sorts ----
__global__ __launch_bounds__(256) void hist_kernel(const int* __restrict__ srcIdx,
                                                   const int* __restrict__ dstIdx,
                                                   int* __restrict__ degD,
                                                   int* __restrict__ degS) {
    int e = blockIdx.x * 256 + threadIdx.x;
    if (e >= N_EDGES) return;
    atomicAdd(&degD[dstIdx[e]], 1);
    atomicAdd(&degS[srcIdx[e]], 1);
}

// 2 blocks x 1024: block 0 scans degD->offD/curD, block 1 scans degS->offS/curS
__global__ __launch_bounds__(1024) void scan_both(const int* __restrict__ degD,
                                                  const int* __restrict__ degS,
                                                  int* __restrict__ offD, int* __restrict__ offS,
                                                  int* __restrict__ curD, int* __restrict__ curS) {
    __shared__ int buf[1024];
    const int CHUNK = 49;  // 1024*49 = 50176 >= 50000
    const int* deg = blockIdx.x ? degS : degD;
    int* off = blockIdx.x ? offS : offD;
    int* cur = blockIdx.x ? curS : curD;
    int tid = threadIdx.x;
    int s0 = tid * CHUNK, s1 = s0 + CHUNK;
    if (s0 > N_NODES) s0 = N_NODES;
    if (s1 > N_NODES) s1 = N_NODES;
    int s = 0;
    for (int i = s0; i < s1; ++i) s += deg[i];
    buf[tid] = s;
    __syncthreads();
    for (int o = 1; o < 1024; o <<= 1) {
        int v = (tid >= o) ? buf[tid - o] : 0;
        __syncthreads();
        buf[tid] += v;
        __syncthreads();
    }
    int run = (tid > 0) ? buf[tid - 1] : 0;
    for (int i = s0; i < s1; ++i) {
        off[i] = run;
        cur[i] = run;
        run += deg[i];
    }
    if (tid == 1023) off[N_NODES] = buf[1023];
}

typedef struct { int e, s; } EdgePair;

__global__ __launch_bounds__(256) void scatter_kernel(const int* __restrict__ srcIdx,
                                                      const int* __restrict__ dstIdx,
                                                      int* __restrict__ curD,
                                                      int* __restrict__ curS,
                                                      int2* __restrict__ sd,
                                                      int* __restrict__ ss_dst) {
    int e = blockIdx.x * 256 + threadIdx.x;
    if (e >= N_EDGES) return;
    int s = srcIdx[e], d = dstIdx[e];
    int p = atomicAdd(&curD[d], 1);
    sd[p] = make_int2(e, s);
    int p2 = atomicAdd(&curS[s], 1);
    ss_dst[p2] = d;
}

// ---- GEMM: out[M,C] = A[M,128]@B + bias. flags: 1=out bf16, 2=A bf16, 4=swizzle cols
// swizzle (per 128-col half): col' = (col&15)*8 + ((col&127)>>4)
__global__ __launch_bounds__(256) void gemm_mfma(const void* __restrict__ Ap,
                                                 const u16* __restrict__ PB,
                                                 const float* __restrict__ bias,
                                                 void* __restrict__ outp,
                                                 int M, int Ctiles, int flags) {
    int tid = threadIdx.x;
    int wave = tid >> 6;
    int lane = tid & 63;
    int strip = blockIdx.x * 4 + wave;
    int row0 = strip * 16;
    if (row0 >= M) return;
    int q = lane >> 4, n = lane & 15;
    int C = Ctiles * 16;

    short8 a[4];
    if (flags & 2) {
        const u16* ap = (const u16*)Ap + (size_t)(row0 + n) * 128 + q * 8;
#pragma unroll
        for (int c = 0; c < 4; ++c) a[c] = *(const short8*)(ap + c * 32);
    } else {
        const float* ap = (const float*)Ap + (size_t)(row0 + n) * 128 + q * 8;
#pragma unroll
        for (int c = 0; c < 4; ++c) {
            f32x4 f0 = *(const f32x4*)(ap + c * 32);
            f32x4 f1 = *(const f32x4*)(ap + c * 32 + 4);
            short8 t;
#pragma unroll
            for (int j = 0; j < 4; ++j) {
                t[j] = (short)f2bf(f0[j]);
                t[4 + j] = (short)f2bf(f1[j]);
            }
            a[c] = t;
        }
    }

    for (int t = 0; t < Ctiles; ++t) {
        f32x4 acc = {0.f, 0.f, 0.f, 0.f};
#pragma unroll
        for (int c = 0; c < 4; ++c) {
            short8 b = *(const short8*)(PB + (((size_t)t * 4 + c) * 64 + lane) * 8);
            acc = __builtin_amdgcn_mfma_f32_16x16x32_bf16(a[c], b, acc, 0, 0, 0);
        }
        int col = t * 16 + n;
        float bv = bias ? bias[col] : 0.f;
        int ocol = col;
        if (flags & 4) ocol = (col & ~127) + (col & 15) * 8 + ((col & 127) >> 4);
#pragma unroll
        for (int r = 0; r < 4; ++r) {
            int row = row0 + q * 4 + r;
            float v = acc[r] + bv;
            if (flags & 1)
                ((u16*)outp)[(size_t)row * C + ocol] = f2bf(v);
            else
                ((float*)outp)[(size_t)row * C + ocol] = v;
        }
    }
}

// ---- fused aggregation: one wave per dst node, edges sorted by dst ----
// agg[n] = sum_seg silu( EA[e]@W3 + T1a[n] + T1b[src_e] )  (bf16 out, plain layout)
// T1 is [N,256] bf16 col-SWIZZLED per half: T1[node*256 + half + n*8 + t] = col t*16+n
__global__ __launch_bounds__(256, 4) void agg_fused(const float* __restrict__ EA,
                                                    const u16* __restrict__ PB3,
                                                    const int* __restrict__ offD,
                                                    const int2* __restrict__ sd,
                                                    const u16* __restrict__ T1,
                                                    u16* __restrict__ agg) {
    int tid = threadIdx.x;
    int wave = tid >> 6;
    int lane = tid & 63;
    int node = blockIdx.x * 4 + wave;
    if (node >= N_NODES) return;
    int q = lane >> 4, n = lane & 15;
    int segS = offD[node], segE = offD[node + 1];

    // own-row (dst) contribution: one 16B load, cols t*16+n for t=0..7
    short8 g1v = *(const short8*)(T1 + (size_t)node * 256 + n * 8);
    float g1[8], rowAcc[8];
#pragma unroll
    for (int t = 0; t < 8; ++t) {
        g1[t] = bf2f((u16)g1v[t]);
        rowAcc[t] = 0.f;
    }

    for (int base = segS; base < segE; base += 16) {
        int er = base + n;
        if (er > segE - 1) er = segE - 1;  // clamp (masked below)
        int2 es = sd[er];                  // {edge id, src}

        // A fragments: 16 edge rows of EA (this lane: row es.e, k = c*32+q*8..+8)
        const float* ap = EA + (size_t)es.x * 128 + q * 8;
        short8 a[4];
#pragma unroll
        for (int c = 0; c < 4; ++c) {
            f32x4 f0 = *(const f32x4*)(ap + c * 32);
            f32x4 f1 = *(const f32x4*)(ap + c * 32 + 4);
            short8 t;
#pragma unroll
            for (int j = 0; j < 4; ++j) {
                t[j] = (short)f2bf(f0[j]);
                t[4 + j] = (short)f2bf(f1[j]);
            }
            a[c] = t;
        }

        // src rows for the 4 C-rows this lane owns (edge base+q*4+r), via shfl
        int srow[4];
        bool val[4];
        short8 tb[4];
#pragma unroll
        for (int r = 0; r < 4; ++r) {
            int idx = base + q * 4 + r;
            val[r] = idx < segE;
            srow[r] = __shfl(es.y, q * 4 + r, 16);
        }
#pragma unroll
        for (int r = 0; r < 4; ++r)
            tb[r] = *(const short8*)(T1 + (size_t)srow[r] * 256 + 128 + n * 8);

#pragma unroll
        for (int t = 0; t < 8; ++t) {
            f32x4 acc = {0.f, 0.f, 0.f, 0.f};
#pragma unroll
            for (int c = 0; c < 4; ++c) {
                short8 b = *(const short8*)(PB3 + (((size_t)t * 4 + c) * 64 + lane) * 8);
                acc = __builtin_amdgcn_mfma_f32_16x16x32_bf16(a[c], b, acc, 0, 0, 0);
            }
#pragma unroll
            for (int r = 0; r < 4; ++r) {
                float v = acc[r] + g1[t] + bf2f((u16)tb[r][t]);
                float m = v / (1.f + __expf(-v));  // SiLU
                rowAcc[t] += val[r] ? m : 0.f;
            }
        }
    }
    // cross-quad reduce -> every lane has full col sum; quads write 2 tiles each
#pragma unroll
    for (int t = 0; t < 8; ++t) {
        float v = rowAcc[t];
        v += __shfl_xor(v, 16, 64);
        v += __shfl_xor(v, 32, 64);
        rowAcc[t] = v;
    }
#pragma unroll
    for (int u = 0; u < 2; ++u) {
        int t = q * 2 + u;
        agg[(size_t)node * 128 + t * 16 + n] = f2bf(rowAcc[t]);
    }
}

// ---- final: out[n] = sum_{e in srcseg(n)} h2[dst_e] + bo   (h2 bf16 plain) ----
__global__ __launch_bounds__(256) void out_gather(const int* __restrict__ offS,
                                                  const int* __restrict__ ss_dst,
                                                  const u16* __restrict__ h2,
                                                  const float* __restrict__ bo,
                                                  float* __restrict__ out) {
    int tid = threadIdx.x;
    int wave = tid >> 6;
    int lane = tid & 63;
    int node = blockIdx.x * 4 + wave;
    if (node >= N_NODES) return;
    int e0 = offS[node], e1 = offS[node + 1];
    float a0 = 0.f, a1 = 0.f;
    int e = e0;
    for (; e + 4 <= e1; e += 4) {
        int d0 = ss_dst[e], d1 = ss_dst[e + 1], d2 = ss_dst[e + 2], d3 = ss_dst[e + 3];
        u32 h0 = *(const u32*)(h2 + (size_t)d0 * 128 + lane * 2);
        u32 h1 = *(const u32*)(h2 + (size_t)d1 * 128 + lane * 2);
        u32 hh2 = *(const u32*)(h2 + (size_t)d2 * 128 + lane * 2);
        u32 h3 = *(const u32*)(h2 + (size_t)d3 * 128 + lane * 2);
        a0 += bf2f((u16)h0) + bf2f((u16)h1) + bf2f((u16)hh2) + bf2f((u16)h3);
        a1 += bf2f((u16)(h0 >> 16)) + bf2f((u16)(h1 >> 16)) +
              bf2f((u16)(hh2 >> 16)) + bf2f((u16)(h3 >> 16));
    }
    for (; e < e1; ++e) {
        int d = ss_dst[e];
        u32 hv = *(const u32*)(h2 + (size_t)d * 128 + lane * 2);
        a0 += bf2f((u16)hv);
        a1 += bf2f((u16)(hv >> 16));
    }
    f32x2 bv = *(const f32x2*)(bo + lane * 2);
    f32x2 o;
    o[0] = a0 + bv[0];
    o[1] = a1 + bv[1];
    *(f32x2*)(out + (size_t)node * 128 + lane * 2) = o;
}

extern "C" void kernel_launch(void* const* d_in, const int* in_sizes, int n_in,
                              void* d_out, int out_size, void* d_ws, size_t ws_size,
                              hipStream_t stream) {
    const float* x  = (const float*)d_in[0];
    const int* ei   = (const int*)d_in[1];
    const float* ea = (const float*)d_in[2];
    const float* We = (const float*)d_in[3];
    const float* be = (const float*)d_in[4];
    const float* Wg = (const float*)d_in[5];
    const float* bg = (const float*)d_in[6];
    // d_in[7]=Wa, d_in[8]=ba: dead — softmax over a size-1 axis is identically 1
    const float* Wo = (const float*)d_in[9];
    const float* bo = (const float*)d_in[10];
    float* out = (float*)d_out;

    const int* srcIdx = ei;            // edge_index[0]
    const int* dstIdx = ei + N_EDGES;  // edge_index[1]

    char* ws = (char*)d_ws;
    u16*   PB1     = (u16*)(ws + 0);          // 64 KiB
    u16*   PB3     = (u16*)(ws + 65536);      // 32 KiB
    u16*   PBgo    = (u16*)(ws + 98304);      // 32 KiB
    float* bias256 = (float*)(ws + 131072);   // 1 KiB
    float* Wgo     = (float*)(ws + 132096);   // 64 KiB
    float* bgo     = (float*)(ws + 197632);   // 512 B
    u16*   T1      = (u16*)(ws + 262144);     // [N,256] bf16 swizzled, 25.6 MB
    u16*   agg     = (u16*)(ws + 25862144);   // [N,128] bf16, 12.8 MB
    u16*   h2      = (u16*)(ws + 38662144);   // [N,128] bf16, 12.8 MB
    int*   degD    = (int*)(ws + 51462144);
    int*   degS    = (int*)(ws + 51662144);
    int*   offD    = (int*)(ws + 51862144);
    int*   offS    = (int*)(ws + 52062160);
    int*   curD    = (int*)(ws + 52262176);
    int*   curS    = (int*)(ws + 52462176);
    int2*  sd      = (int2*)(ws + 52662176);  // 6.4 MB {edge,src} sorted by dst
    int*   ss_dst  = (int*)(ws + 59062176);   // 3.2 MB dst sorted by src

    hipMemsetAsync(degD, 0, 400000, stream);  // degD+degS contiguous

    pack_we<<<24, 256, 0, stream>>>(We, PB1, PB3);
    build_bias256<<<1, 256, 0, stream>>>(be, bias256);
    compute_wgo<<<64, 256, 0, stream>>>(Wg, Wo, bg, Wgo, bgo);
    pack_b<<<8, 256, 0, stream>>>(Wgo, PBgo);

    hist_kernel<<<3125, 256, 0, stream>>>(srcIdx, dstIdx, degD, degS);
    scan_both<<<2, 1024, 0, stream>>>(degD, degS, offD, offS, curD, curS);
    scatter_kernel<<<3125, 256, 0, stream>>>(srcIdx, dstIdx, curD, curS, sd, ss_dst);

    // T1 = [x@W1 + be | x@W2]  (bf16, swizzled cols per half)
    gemm_mfma<<<782, 256, 0, stream>>>(x, PB1, bias256, T1, N_NODES, 16, 1 | 4);

    // agg[n] = segment-sum of silu(...)  — no atomics
    agg_fused<<<12500, 256, 0, stream>>>(ea, PB3, offD, sd, T1, agg);

    // h2 = agg@(Wg@Wo) + bg@Wo  (bf16 in/out, plain layout)
    gemm_mfma<<<782, 256, 0, stream>>>(agg, PBgo, bgo, h2, N_NODES, 8, 1 | 2);

    // out[n] = sum_srcseg h2[dst] + bo  — fused final linear via folded weights
    out_gather<<<12500, 256, 0, stream>>>(offS, ss_dst, h2, bo, out);

    (void)in_sizes; (void)n_in; (void)out_size; (void)ws_size;
}